// Round 1
// baseline (557.568 us; speedup 1.0000x reference)
//
#include <hip/hip_runtime.h>

#define N_NODES 100000
#define N_EDGES 1200000
#define D_IN 256
#define D_OUT 64

// ---------------------------------------------------------------------------
// Kernel 1: transpose W [256][64] -> Wt [64][256] so each output-feature's
// weight column is contiguous (enables wave-uniform scalar loads in GEMM).
// ---------------------------------------------------------------------------
__global__ __launch_bounds__(256) void transpose_w(const float* __restrict__ W,
                                                   float* __restrict__ Wt) {
    int id = blockIdx.x * 256 + threadIdx.x;
    if (id < D_IN * D_OUT) {
        int k = id / D_OUT;
        int d = id % D_OUT;
        Wt[d * D_IN + k] = W[id];
    }
}

// ---------------------------------------------------------------------------
// Kernel 2: support = x @ W.  One wave per 64-row block; lane = row.
// Lane keeps 16 x-values (one K-chunk) in registers; W reads are wave-uniform
// (compiler scalarizes -> s_load + v_fmac with SGPR operand). 64 fp32 acc/lane.
// ---------------------------------------------------------------------------
__global__ __launch_bounds__(256) void gemm_xw(const float* __restrict__ x,
                                               const float* __restrict__ Wt,
                                               float* __restrict__ support) {
    const int wave = threadIdx.x >> 6;
    const int lane = threadIdx.x & 63;
    const int rowblock = blockIdx.x * 4 + wave;
    const int row = rowblock * 64 + lane;
    const bool valid = (row < N_NODES);
    const int r = valid ? row : (N_NODES - 1);
    const float* __restrict__ xrow = x + (size_t)r * D_IN;

    float acc[D_OUT];
#pragma unroll
    for (int d = 0; d < D_OUT; ++d) acc[d] = 0.0f;

#pragma unroll 1
    for (int c = 0; c < D_IN / 16; ++c) {
        // load this lane's 16 contiguous x values (4x dwordx4)
        float xr[16];
#pragma unroll
        for (int q = 0; q < 4; ++q) {
            float4 a = ((const float4*)(xrow + c * 16))[q];
            xr[q * 4 + 0] = a.x;
            xr[q * 4 + 1] = a.y;
            xr[q * 4 + 2] = a.z;
            xr[q * 4 + 3] = a.w;
        }
#pragma unroll
        for (int d = 0; d < D_OUT; ++d) {
            const float* __restrict__ wp = Wt + d * D_IN + c * 16;
#pragma unroll
            for (int kk = 0; kk < 16; ++kk) {
                acc[d] = fmaf(xr[kk], wp[kk], acc[d]);
            }
        }
    }

    if (valid) {
        float* __restrict__ op = support + (size_t)row * D_OUT;
#pragma unroll
        for (int d = 0; d < D_OUT; d += 4) {
            float4 v;
            v.x = acc[d + 0];
            v.y = acc[d + 1];
            v.z = acc[d + 2];
            v.w = acc[d + 3];
            *(float4*)(op + d) = v;
        }
    }
}

// ---------------------------------------------------------------------------
// Kernel 3: scatter-add.  thread = (edge, feature d).  64 lanes share one
// edge -> index loads broadcast, gather of support[col] is one coalesced
// 256B read, atomicAdd into out[row].
// ---------------------------------------------------------------------------
__global__ __launch_bounds__(256) void spmm_scatter(const int* __restrict__ erow,
                                                    const int* __restrict__ ecol,
                                                    const float* __restrict__ eval,
                                                    const float* __restrict__ support,
                                                    float* __restrict__ out) {
    long long id = (long long)blockIdx.x * 256 + threadIdx.x;
    int e = (int)(id >> 6);
    int d = (int)(id & 63);
    if (e < N_EDGES) {
        int rw = erow[e];
        int cl = ecol[e];
        float v = eval[e];
        float m = v * support[(size_t)cl * D_OUT + d];
        atomicAdd(&out[(size_t)rw * D_OUT + d], m);
    }
}

// ---------------------------------------------------------------------------
// Kernel 4: in-place ReLU on out (float4).
// ---------------------------------------------------------------------------
__global__ __launch_bounds__(256) void relu_k(float* __restrict__ out, int n4) {
    int id = blockIdx.x * 256 + threadIdx.x;
    if (id < n4) {
        float4* p = (float4*)out + id;
        float4 v = *p;
        v.x = v.x > 0.0f ? v.x : 0.0f;
        v.y = v.y > 0.0f ? v.y : 0.0f;
        v.z = v.z > 0.0f ? v.z : 0.0f;
        v.w = v.w > 0.0f ? v.w : 0.0f;
        *p = v;
    }
}

extern "C" void kernel_launch(void* const* d_in, const int* in_sizes, int n_in,
                              void* d_out, int out_size, void* d_ws, size_t ws_size,
                              hipStream_t stream) {
    const float* x    = (const float*)d_in[0];
    const int*   erow = (const int*)d_in[1];
    const int*   ecol = (const int*)d_in[2];
    const float* eval = (const float*)d_in[3];
    const float* W    = (const float*)d_in[4];
    float* out = (float*)d_out;

    // workspace layout: support [N_NODES*D_OUT] fp32, then Wt [D_OUT*D_IN] fp32
    float* support = (float*)d_ws;
    float* Wt = support + (size_t)N_NODES * D_OUT;

    // zero the output accumulator (harness poisons it)
    hipMemsetAsync(d_out, 0, (size_t)out_size * sizeof(float), stream);

    // 1) transpose W
    transpose_w<<<(D_IN * D_OUT + 255) / 256, 256, 0, stream>>>(W, Wt);

    // 2) GEMM: support = x @ W
    {
        int rowblocks = (N_NODES + 63) / 64;          // 1563
        int blocks = (rowblocks + 3) / 4;             // 391 (4 waves/block)
        gemm_xw<<<blocks, 256, 0, stream>>>(x, Wt, support);
    }

    // 3) scatter-add over edges
    {
        long long total = (long long)N_EDGES * D_OUT; // 76.8M threads
        int blocks = (int)((total + 255) / 256);      // 300000
        spmm_scatter<<<blocks, 256, 0, stream>>>(erow, ecol, eval, support, out);
    }

    // 4) ReLU in place
    {
        int n4 = out_size / 4;
        relu_k<<<(n4 + 255) / 256, 256, 0, stream>>>(out, n4);
    }
}

// Round 2
// 540.054 us; speedup vs baseline: 1.0324x; 1.0324x over previous
//
#include <hip/hip_runtime.h>
#include <hip/hip_bf16.h>

#define N_NODES 100000
#define N_EDGES 1200000
#define D_IN 256
#define D_OUT 64
#define N_TILES (N_NODES / 16)   // 6250 row tiles of 16

typedef __bf16 bf16_t;
typedef bf16_t bf16x8 __attribute__((ext_vector_type(8)));
typedef float f32x4 __attribute__((ext_vector_type(4)));

// ---------------------------------------------------------------------------
// Kernel 1: pack W[256][64] (fp32) into MFMA B-fragment order, bf16.
// Flat bf16 index: ((kk*4 + n)*64 + lane)*8 + i
//   maps to W[k][c] with k = kk*32 + (lane>>4)*8 + i, c = n*16 + (lane&15).
// ---------------------------------------------------------------------------
__global__ __launch_bounds__(256) void pack_w(const float* __restrict__ W,
                                              bf16_t* __restrict__ Wpack) {
    int id = blockIdx.x * 256 + threadIdx.x;
    if (id < D_IN * D_OUT) {
        int i  = id & 7;
        int l  = (id >> 3) & 63;
        int n  = (id >> 9) & 3;
        int kk = id >> 11;
        int k = kk * 32 + (l >> 4) * 8 + i;
        int c = n * 16 + (l & 15);
        Wpack[id] = (bf16_t)W[k * D_OUT + c];
    }
}

// ---------------------------------------------------------------------------
// Kernel 2: support(bf16) = x @ W via mfma_f32_16x16x32_bf16.
// Wave = one 16-row tile, all 64 output cols (4 16x16 tiles, 16 acc VGPRs).
// A-frag: lane holds x[tile*16 + (l&15)][kk*32 + (l>>4)*8 + i], i=0..7.
// C/D layout (m89-verified): col = lane&15, row = (lane>>4)*4 + reg.
// ---------------------------------------------------------------------------
__global__ __launch_bounds__(256) void gemm_mfma(const float* __restrict__ x,
                                                 const bf16x8* __restrict__ Wpack,
                                                 bf16_t* __restrict__ support) {
    int wave = threadIdx.x >> 6;
    int lane = threadIdx.x & 63;
    int tile = blockIdx.x * 4 + wave;
    if (tile >= N_TILES) return;
    int lrow = lane & 15;
    int g    = lane >> 4;

    const float* __restrict__ xp = x + (size_t)(tile * 16 + lrow) * D_IN + g * 8;

    f32x4 acc0 = {0.f, 0.f, 0.f, 0.f};
    f32x4 acc1 = {0.f, 0.f, 0.f, 0.f};
    f32x4 acc2 = {0.f, 0.f, 0.f, 0.f};
    f32x4 acc3 = {0.f, 0.f, 0.f, 0.f};

#pragma unroll
    for (int kk = 0; kk < 8; ++kk) {
        float4 a0 = *(const float4*)(xp + kk * 32);
        float4 a1 = *(const float4*)(xp + kk * 32 + 4);
        bf16x8 a;
        a[0] = (bf16_t)a0.x; a[1] = (bf16_t)a0.y;
        a[2] = (bf16_t)a0.z; a[3] = (bf16_t)a0.w;
        a[4] = (bf16_t)a1.x; a[5] = (bf16_t)a1.y;
        a[6] = (bf16_t)a1.z; a[7] = (bf16_t)a1.w;

        bf16x8 b0 = Wpack[(kk * 4 + 0) * 64 + lane];
        bf16x8 b1 = Wpack[(kk * 4 + 1) * 64 + lane];
        bf16x8 b2 = Wpack[(kk * 4 + 2) * 64 + lane];
        bf16x8 b3 = Wpack[(kk * 4 + 3) * 64 + lane];

        acc0 = __builtin_amdgcn_mfma_f32_16x16x32_bf16(a, b0, acc0, 0, 0, 0);
        acc1 = __builtin_amdgcn_mfma_f32_16x16x32_bf16(a, b1, acc1, 0, 0, 0);
        acc2 = __builtin_amdgcn_mfma_f32_16x16x32_bf16(a, b2, acc2, 0, 0, 0);
        acc3 = __builtin_amdgcn_mfma_f32_16x16x32_bf16(a, b3, acc3, 0, 0, 0);
    }

    bf16_t* __restrict__ sp = support + (size_t)tile * 16 * D_OUT;
#pragma unroll
    for (int r = 0; r < 4; ++r) {
        int row = g * 4 + r;
        sp[row * D_OUT +  0 + lrow] = (bf16_t)acc0[r];
        sp[row * D_OUT + 16 + lrow] = (bf16_t)acc1[r];
        sp[row * D_OUT + 32 + lrow] = (bf16_t)acc2[r];
        sp[row * D_OUT + 48 + lrow] = (bf16_t)acc3[r];
    }
}

// ---------------------------------------------------------------------------
// Kernel 3: histogram of edge destination rows.
// ---------------------------------------------------------------------------
__global__ __launch_bounds__(256) void hist_k(const int* __restrict__ erow,
                                              int* __restrict__ counts) {
    int e = blockIdx.x * 256 + threadIdx.x;
    if (e < N_EDGES) atomicAdd(&counts[erow[e]], 1);
}

// ---------------------------------------------------------------------------
// Kernel 4: single-block exclusive scan of counts[100000] -> offsets[100001],
// plus cursor[] = offsets[] copy for the fill pass. Two passes over counts
// (keeps VGPRs low), 1024 threads, CHUNK=98 contiguous elems each.
// ---------------------------------------------------------------------------
#define SCAN_T 1024
#define SCAN_CHUNK 98   // 1024*98 >= 100000
__global__ __launch_bounds__(SCAN_T) void scan_k(const int* __restrict__ counts,
                                                 int* __restrict__ offsets,
                                                 int* __restrict__ cursor) {
    __shared__ int sh[SCAN_T];
    int t = threadIdx.x;
    int base = t * SCAN_CHUNK;
    int sum = 0;
    for (int i = 0; i < SCAN_CHUNK; ++i) {
        int idx = base + i;
        if (idx < N_NODES) sum += counts[idx];
    }
    sh[t] = sum;
    __syncthreads();
    // Hillis-Steele inclusive scan over 1024 partials
    for (int off = 1; off < SCAN_T; off <<= 1) {
        int add = (t >= off) ? sh[t - off] : 0;
        __syncthreads();
        sh[t] += add;
        __syncthreads();
    }
    int run = (t == 0) ? 0 : sh[t - 1];
    for (int i = 0; i < SCAN_CHUNK; ++i) {
        int idx = base + i;
        if (idx < N_NODES) {
            offsets[idx] = run;
            cursor[idx]  = run;
            run += counts[idx];
        }
    }
    if (t == SCAN_T - 1) offsets[N_NODES] = sh[SCAN_T - 1];
}

// ---------------------------------------------------------------------------
// Kernel 5: scatter edges into CSR slots (int atomics on cursors only).
// ---------------------------------------------------------------------------
__global__ __launch_bounds__(256) void fill_k(const int* __restrict__ erow,
                                              const int* __restrict__ ecol,
                                              const float* __restrict__ eval,
                                              int* __restrict__ cursor,
                                              int* __restrict__ csr_col,
                                              float* __restrict__ csr_val) {
    int e = blockIdx.x * 256 + threadIdx.x;
    if (e < N_EDGES) {
        int r = erow[e];
        int pos = atomicAdd(&cursor[r], 1);
        csr_col[pos] = ecol[e];
        csr_val[pos] = eval[e];
    }
}

// ---------------------------------------------------------------------------
// Kernel 6: aggregate + ReLU. One wave per node, lane = feature.
// Gather support[col] rows (128B coalesced bf16), accumulate fp32, no atomics.
// Every output element written (degree-0 nodes -> 0), so no memset needed.
// ---------------------------------------------------------------------------
__global__ __launch_bounds__(256) void agg_k(const int* __restrict__ offsets,
                                             const int* __restrict__ csr_col,
                                             const float* __restrict__ csr_val,
                                             const bf16_t* __restrict__ support,
                                             float* __restrict__ out) {
    int node = blockIdx.x * 4 + (threadIdx.x >> 6);
    int lane = threadIdx.x & 63;
    if (node >= N_NODES) return;
    int s = offsets[node];
    int e = offsets[node + 1];
    float acc = 0.f;
    for (int p = s; p < e; ++p) {
        int c   = csr_col[p];
        float v = csr_val[p];
        acc = fmaf(v, (float)support[(size_t)c * D_OUT + lane], acc);
    }
    out[(size_t)node * D_OUT + lane] = acc > 0.f ? acc : 0.f;
}

extern "C" void kernel_launch(void* const* d_in, const int* in_sizes, int n_in,
                              void* d_out, int out_size, void* d_ws, size_t ws_size,
                              hipStream_t stream) {
    const float* x    = (const float*)d_in[0];
    const int*   erow = (const int*)d_in[1];
    const int*   ecol = (const int*)d_in[2];
    const float* eval = (const float*)d_in[3];
    const float* W    = (const float*)d_in[4];
    float* out = (float*)d_out;

    // ---- workspace layout (23.6 MB total) ----
    char* ws = (char*)d_ws;
    bf16_t* support = (bf16_t*)ws;                                   // 12,800,000 B
    bf16_t* WpackS  = (bf16_t*)(ws + 12800000);                      //     32,768 B
    int*    counts  = (int*)(ws + 12800000 + 32768);                 //    400,000 B
    int*    offsets = counts + N_NODES;                              //    400,004 B
    int*    cursor  = offsets + (N_NODES + 1);                       //    400,000 B
    int*    csr_col = cursor + N_NODES;                              //  4,800,000 B
    float*  csr_val = (float*)(csr_col + N_EDGES);                   //  4,800,000 B

    // 1) pack W into bf16 MFMA B-fragments
    pack_w<<<(D_IN * D_OUT + 255) / 256, 256, 0, stream>>>(W, WpackS);

    // 2) support = x @ W (bf16 MFMA)
    gemm_mfma<<<(N_TILES + 3) / 4, 256, 0, stream>>>(x, (const bf16x8*)WpackS, support);

    // 3) CSR build: histogram -> scan -> fill
    hipMemsetAsync(counts, 0, (size_t)N_NODES * sizeof(int), stream);
    hist_k<<<(N_EDGES + 255) / 256, 256, 0, stream>>>(erow, counts);
    scan_k<<<1, SCAN_T, 0, stream>>>(counts, offsets, cursor);
    fill_k<<<(N_EDGES + 255) / 256, 256, 0, stream>>>(erow, ecol, eval, cursor,
                                                      csr_col, csr_val);

    // 4) aggregate + ReLU (no atomics, writes every output element)
    agg_k<<<(N_NODES + 3) / 4, 256, 0, stream>>>(offsets, csr_col, csr_val,
                                                 support, out);
}

// Round 3
// 285.795 us; speedup vs baseline: 1.9509x; 1.8897x over previous
//
#include <hip/hip_runtime.h>
#include <hip/hip_bf16.h>

#define N_NODES 100000
#define N_EDGES 1200000
#define D_IN 256
#define D_OUT 64
#define N_TILES (N_NODES / 16)   // 6250 row tiles of 16

#define SCAN_BLOCK 1024                                  // counts per block
#define SCAN_NB ((N_NODES + SCAN_BLOCK - 1) / SCAN_BLOCK) // 98

typedef __bf16 bf16_t;
typedef bf16_t bf16x8 __attribute__((ext_vector_type(8)));
typedef float f32x4 __attribute__((ext_vector_type(4)));

// ---------------------------------------------------------------------------
// Kernel 1: pack W[256][64] (fp32) into MFMA B-fragment order, bf16.
// ---------------------------------------------------------------------------
__global__ __launch_bounds__(256) void pack_w(const float* __restrict__ W,
                                              bf16_t* __restrict__ Wpack) {
    int id = blockIdx.x * 256 + threadIdx.x;
    if (id < D_IN * D_OUT) {
        int i  = id & 7;
        int l  = (id >> 3) & 63;
        int n  = (id >> 9) & 3;
        int kk = id >> 11;
        int k = kk * 32 + (l >> 4) * 8 + i;
        int c = n * 16 + (l & 15);
        Wpack[id] = (bf16_t)W[k * D_OUT + c];
    }
}

// ---------------------------------------------------------------------------
// Kernel 2: support(bf16) = x @ W via mfma_f32_16x16x32_bf16.
// ---------------------------------------------------------------------------
__global__ __launch_bounds__(256) void gemm_mfma(const float* __restrict__ x,
                                                 const bf16x8* __restrict__ Wpack,
                                                 bf16_t* __restrict__ support) {
    int wave = threadIdx.x >> 6;
    int lane = threadIdx.x & 63;
    int tile = blockIdx.x * 4 + wave;
    if (tile >= N_TILES) return;
    int lrow = lane & 15;
    int g    = lane >> 4;

    const float* __restrict__ xp = x + (size_t)(tile * 16 + lrow) * D_IN + g * 8;

    f32x4 acc0 = {0.f, 0.f, 0.f, 0.f};
    f32x4 acc1 = {0.f, 0.f, 0.f, 0.f};
    f32x4 acc2 = {0.f, 0.f, 0.f, 0.f};
    f32x4 acc3 = {0.f, 0.f, 0.f, 0.f};

#pragma unroll
    for (int kk = 0; kk < 8; ++kk) {
        float4 a0 = *(const float4*)(xp + kk * 32);
        float4 a1 = *(const float4*)(xp + kk * 32 + 4);
        bf16x8 a;
        a[0] = (bf16_t)a0.x; a[1] = (bf16_t)a0.y;
        a[2] = (bf16_t)a0.z; a[3] = (bf16_t)a0.w;
        a[4] = (bf16_t)a1.x; a[5] = (bf16_t)a1.y;
        a[6] = (bf16_t)a1.z; a[7] = (bf16_t)a1.w;

        bf16x8 b0 = Wpack[(kk * 4 + 0) * 64 + lane];
        bf16x8 b1 = Wpack[(kk * 4 + 1) * 64 + lane];
        bf16x8 b2 = Wpack[(kk * 4 + 2) * 64 + lane];
        bf16x8 b3 = Wpack[(kk * 4 + 3) * 64 + lane];

        acc0 = __builtin_amdgcn_mfma_f32_16x16x32_bf16(a, b0, acc0, 0, 0, 0);
        acc1 = __builtin_amdgcn_mfma_f32_16x16x32_bf16(a, b1, acc1, 0, 0, 0);
        acc2 = __builtin_amdgcn_mfma_f32_16x16x32_bf16(a, b2, acc2, 0, 0, 0);
        acc3 = __builtin_amdgcn_mfma_f32_16x16x32_bf16(a, b3, acc3, 0, 0, 0);
    }

    bf16_t* __restrict__ sp = support + (size_t)tile * 16 * D_OUT;
#pragma unroll
    for (int r = 0; r < 4; ++r) {
        int row = g * 4 + r;
        sp[row * D_OUT +  0 + lrow] = (bf16_t)acc0[r];
        sp[row * D_OUT + 16 + lrow] = (bf16_t)acc1[r];
        sp[row * D_OUT + 32 + lrow] = (bf16_t)acc2[r];
        sp[row * D_OUT + 48 + lrow] = (bf16_t)acc3[r];
    }
}

// ---------------------------------------------------------------------------
// Kernel 3: histogram of edge destination rows.
// ---------------------------------------------------------------------------
__global__ __launch_bounds__(256) void hist_k(const int* __restrict__ erow,
                                              int* __restrict__ counts) {
    int e = blockIdx.x * 256 + threadIdx.x;
    if (e < N_EDGES) atomicAdd(&counts[erow[e]], 1);
}

// ---------------------------------------------------------------------------
// Kernel 4a: per-block partial sums of counts (1024 counts per block).
// ---------------------------------------------------------------------------
__global__ __launch_bounds__(256) void partial_k(const int* __restrict__ counts,
                                                 int* __restrict__ bsum) {
    int b = blockIdx.x, t = threadIdx.x;
    int base = b * SCAN_BLOCK + t * 4;
    int s = 0;
    if (base + 3 < N_NODES) {
        int4 v = *(const int4*)(counts + base);
        s = v.x + v.y + v.z + v.w;
    } else {
#pragma unroll
        for (int i = 0; i < 4; ++i)
            if (base + i < N_NODES) s += counts[base + i];
    }
#pragma unroll
    for (int off = 32; off > 0; off >>= 1) s += __shfl_down(s, off);
    __shared__ int sh[4];
    if ((t & 63) == 0) sh[t >> 6] = s;
    __syncthreads();
    if (t == 0) bsum[b] = sh[0] + sh[1] + sh[2] + sh[3];
}

// ---------------------------------------------------------------------------
// Kernel 4b: scan the 98 block sums (1 tiny block). Also writes offsets[N].
// ---------------------------------------------------------------------------
__global__ __launch_bounds__(128) void scan_bsum_k(const int* __restrict__ bsum,
                                                   int* __restrict__ bpre,
                                                   int* __restrict__ offsets) {
    __shared__ int sh[128];
    int t = threadIdx.x;
    int v = (t < SCAN_NB) ? bsum[t] : 0;
    sh[t] = v;
    __syncthreads();
    for (int off = 1; off < 128; off <<= 1) {
        int add = (t >= off) ? sh[t - off] : 0;
        __syncthreads();
        sh[t] += add;
        __syncthreads();
    }
    if (t < SCAN_NB) bpre[t] = sh[t] - v;
    if (t == 127) offsets[N_NODES] = sh[127];
}

// ---------------------------------------------------------------------------
// Kernel 4c: block-local scan + global prefix -> offsets, cursor.
// ---------------------------------------------------------------------------
__global__ __launch_bounds__(256) void emit_k(const int* __restrict__ counts,
                                              const int* __restrict__ bpre,
                                              int* __restrict__ offsets,
                                              int* __restrict__ cursor) {
    __shared__ int sh[256];
    int b = blockIdx.x, t = threadIdx.x;
    int base = b * SCAN_BLOCK + t * 4;
    int c0 = 0, c1 = 0, c2 = 0, c3 = 0;
    if (base + 3 < N_NODES) {
        int4 v = *(const int4*)(counts + base);
        c0 = v.x; c1 = v.y; c2 = v.z; c3 = v.w;
    } else {
        if (base + 0 < N_NODES) c0 = counts[base + 0];
        if (base + 1 < N_NODES) c1 = counts[base + 1];
        if (base + 2 < N_NODES) c2 = counts[base + 2];
        if (base + 3 < N_NODES) c3 = counts[base + 3];
    }
    int sum4 = c0 + c1 + c2 + c3;
    sh[t] = sum4;
    __syncthreads();
    for (int off = 1; off < 256; off <<= 1) {
        int add = (t >= off) ? sh[t - off] : 0;
        __syncthreads();
        sh[t] += add;
        __syncthreads();
    }
    int run = bpre[b] + sh[t] - sum4;
    if (base + 0 < N_NODES) { offsets[base + 0] = run; cursor[base + 0] = run; run += c0; }
    if (base + 1 < N_NODES) { offsets[base + 1] = run; cursor[base + 1] = run; run += c1; }
    if (base + 2 < N_NODES) { offsets[base + 2] = run; cursor[base + 2] = run; run += c2; }
    if (base + 3 < N_NODES) { offsets[base + 3] = run; cursor[base + 3] = run; run += c3; }
}

// ---------------------------------------------------------------------------
// Kernel 5: scatter edges into CSR slots (int atomics on cursors only).
// ---------------------------------------------------------------------------
__global__ __launch_bounds__(256) void fill_k(const int* __restrict__ erow,
                                              const int* __restrict__ ecol,
                                              const float* __restrict__ eval,
                                              int* __restrict__ cursor,
                                              int* __restrict__ csr_col,
                                              float* __restrict__ csr_val) {
    int e = blockIdx.x * 256 + threadIdx.x;
    if (e < N_EDGES) {
        int r = erow[e];
        int pos = atomicAdd(&cursor[r], 1);
        csr_col[pos] = ecol[e];
        csr_val[pos] = eval[e];
    }
}

// ---------------------------------------------------------------------------
// Kernel 6: aggregate + ReLU. One wave per node, lane = feature.
// ---------------------------------------------------------------------------
__global__ __launch_bounds__(256) void agg_k(const int* __restrict__ offsets,
                                             const int* __restrict__ csr_col,
                                             const float* __restrict__ csr_val,
                                             const bf16_t* __restrict__ support,
                                             float* __restrict__ out) {
    int node = blockIdx.x * 4 + (threadIdx.x >> 6);
    int lane = threadIdx.x & 63;
    if (node >= N_NODES) return;
    int s = offsets[node];
    int e = offsets[node + 1];
    float acc = 0.f;
    for (int p = s; p < e; ++p) {
        int c   = csr_col[p];
        float v = csr_val[p];
        acc = fmaf(v, (float)support[(size_t)c * D_OUT + lane], acc);
    }
    out[(size_t)node * D_OUT + lane] = acc > 0.f ? acc : 0.f;
}

extern "C" void kernel_launch(void* const* d_in, const int* in_sizes, int n_in,
                              void* d_out, int out_size, void* d_ws, size_t ws_size,
                              hipStream_t stream) {
    const float* x    = (const float*)d_in[0];
    const int*   erow = (const int*)d_in[1];
    const int*   ecol = (const int*)d_in[2];
    const float* eval = (const float*)d_in[3];
    const float* W    = (const float*)d_in[4];
    float* out = (float*)d_out;

    // ---- workspace layout ----
    char* ws = (char*)d_ws;
    bf16_t* support = (bf16_t*)ws;                                   // 12,800,000 B
    bf16_t* WpackS  = (bf16_t*)(ws + 12800000);                      //     32,768 B
    int*    counts  = (int*)(ws + 12800000 + 32768);                 //    400,000 B
    int*    offsets = counts + N_NODES;                              //    400,004 B
    int*    cursor  = offsets + (N_NODES + 1);                       //    400,000 B
    int*    csr_col = cursor + N_NODES;                              //  4,800,000 B
    float*  csr_val = (float*)(csr_col + N_EDGES);                   //  4,800,000 B
    int*    bsum    = (int*)(csr_val + N_EDGES);                     //        392 B
    int*    bpre    = bsum + SCAN_NB;                                //        392 B

    // 1) pack W into bf16 MFMA B-fragments
    pack_w<<<(D_IN * D_OUT + 255) / 256, 256, 0, stream>>>(W, WpackS);

    // 2) support = x @ W (bf16 MFMA)
    gemm_mfma<<<(N_TILES + 3) / 4, 256, 0, stream>>>(x, (const bf16x8*)WpackS, support);

    // 3) CSR build: histogram -> hierarchical scan -> fill
    hipMemsetAsync(counts, 0, (size_t)N_NODES * sizeof(int), stream);
    hist_k<<<(N_EDGES + 255) / 256, 256, 0, stream>>>(erow, counts);
    partial_k<<<SCAN_NB, 256, 0, stream>>>(counts, bsum);
    scan_bsum_k<<<1, 128, 0, stream>>>(bsum, bpre, offsets);
    emit_k<<<SCAN_NB, 256, 0, stream>>>(counts, bpre, offsets, cursor);
    fill_k<<<(N_EDGES + 255) / 256, 256, 0, stream>>>(erow, ecol, eval, cursor,
                                                      csr_col, csr_val);

    // 4) aggregate + ReLU (no atomics, writes every output element)
    agg_k<<<(N_NODES + 3) / 4, 256, 0, stream>>>(offsets, csr_col, csr_val,
                                                 support, out);
}

// Round 4
// 224.496 us; speedup vs baseline: 2.4836x; 1.2731x over previous
//
#include <hip/hip_runtime.h>
#include <hip/hip_bf16.h>

#define N_NODES 100000
#define N_EDGES 1200000
#define D_IN 256
#define D_OUT 64
#define N_TILES (N_NODES / 16)   // 6250 row tiles of 16

#define SCAN_BLOCK 1024                                  // counts per block
#define SCAN_NB ((N_NODES + SCAN_BLOCK - 1) / SCAN_BLOCK) // 98

typedef __bf16 bf16_t;
typedef bf16_t bf16x8 __attribute__((ext_vector_type(8)));
typedef float f32x4 __attribute__((ext_vector_type(4)));

// ---------------------------------------------------------------------------
// Kernel 1: pack W[256][64] (fp32) into MFMA B-fragment order, bf16.
// ---------------------------------------------------------------------------
__global__ __launch_bounds__(256) void pack_w(const float* __restrict__ W,
                                              bf16_t* __restrict__ Wpack) {
    int id = blockIdx.x * 256 + threadIdx.x;
    if (id < D_IN * D_OUT) {
        int i  = id & 7;
        int l  = (id >> 3) & 63;
        int n  = (id >> 9) & 3;
        int kk = id >> 11;
        int k = kk * 32 + (l >> 4) * 8 + i;
        int c = n * 16 + (l & 15);
        Wpack[id] = (bf16_t)W[k * D_OUT + c];
    }
}

// ---------------------------------------------------------------------------
// Kernel 2: support(bf16) = x @ W via mfma_f32_16x16x32_bf16.
// ---------------------------------------------------------------------------
__global__ __launch_bounds__(256) void gemm_mfma(const float* __restrict__ x,
                                                 const bf16x8* __restrict__ Wpack,
                                                 bf16_t* __restrict__ support) {
    int wave = threadIdx.x >> 6;
    int lane = threadIdx.x & 63;
    int tile = blockIdx.x * 4 + wave;
    if (tile >= N_TILES) return;
    int lrow = lane & 15;
    int g    = lane >> 4;

    const float* __restrict__ xp = x + (size_t)(tile * 16 + lrow) * D_IN + g * 8;

    f32x4 acc0 = {0.f, 0.f, 0.f, 0.f};
    f32x4 acc1 = {0.f, 0.f, 0.f, 0.f};
    f32x4 acc2 = {0.f, 0.f, 0.f, 0.f};
    f32x4 acc3 = {0.f, 0.f, 0.f, 0.f};

#pragma unroll
    for (int kk = 0; kk < 8; ++kk) {
        float4 a0 = *(const float4*)(xp + kk * 32);
        float4 a1 = *(const float4*)(xp + kk * 32 + 4);
        bf16x8 a;
        a[0] = (bf16_t)a0.x; a[1] = (bf16_t)a0.y;
        a[2] = (bf16_t)a0.z; a[3] = (bf16_t)a0.w;
        a[4] = (bf16_t)a1.x; a[5] = (bf16_t)a1.y;
        a[6] = (bf16_t)a1.z; a[7] = (bf16_t)a1.w;

        bf16x8 b0 = Wpack[(kk * 4 + 0) * 64 + lane];
        bf16x8 b1 = Wpack[(kk * 4 + 1) * 64 + lane];
        bf16x8 b2 = Wpack[(kk * 4 + 2) * 64 + lane];
        bf16x8 b3 = Wpack[(kk * 4 + 3) * 64 + lane];

        acc0 = __builtin_amdgcn_mfma_f32_16x16x32_bf16(a, b0, acc0, 0, 0, 0);
        acc1 = __builtin_amdgcn_mfma_f32_16x16x32_bf16(a, b1, acc1, 0, 0, 0);
        acc2 = __builtin_amdgcn_mfma_f32_16x16x32_bf16(a, b2, acc2, 0, 0, 0);
        acc3 = __builtin_amdgcn_mfma_f32_16x16x32_bf16(a, b3, acc3, 0, 0, 0);
    }

    bf16_t* __restrict__ sp = support + (size_t)tile * 16 * D_OUT;
#pragma unroll
    for (int r = 0; r < 4; ++r) {
        int row = g * 4 + r;
        sp[row * D_OUT +  0 + lrow] = (bf16_t)acc0[r];
        sp[row * D_OUT + 16 + lrow] = (bf16_t)acc1[r];
        sp[row * D_OUT + 32 + lrow] = (bf16_t)acc2[r];
        sp[row * D_OUT + 48 + lrow] = (bf16_t)acc3[r];
    }
}

// ---------------------------------------------------------------------------
// Kernel 3: histogram of edge destination rows.
// ---------------------------------------------------------------------------
__global__ __launch_bounds__(256) void hist_k(const int* __restrict__ erow,
                                              int* __restrict__ counts) {
    int e = blockIdx.x * 256 + threadIdx.x;
    if (e < N_EDGES) atomicAdd(&counts[erow[e]], 1);
}

// ---------------------------------------------------------------------------
// Kernel 4a: per-block partial sums of counts (1024 counts per block).
// ---------------------------------------------------------------------------
__global__ __launch_bounds__(256) void partial_k(const int* __restrict__ counts,
                                                 int* __restrict__ bsum) {
    int b = blockIdx.x, t = threadIdx.x;
    int base = b * SCAN_BLOCK + t * 4;
    int s = 0;
    if (base + 3 < N_NODES) {
        int4 v = *(const int4*)(counts + base);
        s = v.x + v.y + v.z + v.w;
    } else {
#pragma unroll
        for (int i = 0; i < 4; ++i)
            if (base + i < N_NODES) s += counts[base + i];
    }
#pragma unroll
    for (int off = 32; off > 0; off >>= 1) s += __shfl_down(s, off);
    __shared__ int sh[4];
    if ((t & 63) == 0) sh[t >> 6] = s;
    __syncthreads();
    if (t == 0) bsum[b] = sh[0] + sh[1] + sh[2] + sh[3];
}

// ---------------------------------------------------------------------------
// Kernel 4b: scan the 98 block sums (1 tiny block). Also writes offsets[N].
// ---------------------------------------------------------------------------
__global__ __launch_bounds__(128) void scan_bsum_k(const int* __restrict__ bsum,
                                                   int* __restrict__ bpre,
                                                   int* __restrict__ offsets) {
    __shared__ int sh[128];
    int t = threadIdx.x;
    int v = (t < SCAN_NB) ? bsum[t] : 0;
    sh[t] = v;
    __syncthreads();
    for (int off = 1; off < 128; off <<= 1) {
        int add = (t >= off) ? sh[t - off] : 0;
        __syncthreads();
        sh[t] += add;
        __syncthreads();
    }
    if (t < SCAN_NB) bpre[t] = sh[t] - v;
    if (t == 127) offsets[N_NODES] = sh[127];
}

// ---------------------------------------------------------------------------
// Kernel 4c: block-local scan + global prefix -> offsets, cursor.
// ---------------------------------------------------------------------------
__global__ __launch_bounds__(256) void emit_k(const int* __restrict__ counts,
                                              const int* __restrict__ bpre,
                                              int* __restrict__ offsets,
                                              int* __restrict__ cursor) {
    __shared__ int sh[256];
    int b = blockIdx.x, t = threadIdx.x;
    int base = b * SCAN_BLOCK + t * 4;
    int c0 = 0, c1 = 0, c2 = 0, c3 = 0;
    if (base + 3 < N_NODES) {
        int4 v = *(const int4*)(counts + base);
        c0 = v.x; c1 = v.y; c2 = v.z; c3 = v.w;
    } else {
        if (base + 0 < N_NODES) c0 = counts[base + 0];
        if (base + 1 < N_NODES) c1 = counts[base + 1];
        if (base + 2 < N_NODES) c2 = counts[base + 2];
        if (base + 3 < N_NODES) c3 = counts[base + 3];
    }
    int sum4 = c0 + c1 + c2 + c3;
    sh[t] = sum4;
    __syncthreads();
    for (int off = 1; off < 256; off <<= 1) {
        int add = (t >= off) ? sh[t - off] : 0;
        __syncthreads();
        sh[t] += add;
        __syncthreads();
    }
    int run = bpre[b] + sh[t] - sum4;
    if (base + 0 < N_NODES) { offsets[base + 0] = run; cursor[base + 0] = run; run += c0; }
    if (base + 1 < N_NODES) { offsets[base + 1] = run; cursor[base + 1] = run; run += c1; }
    if (base + 2 < N_NODES) { offsets[base + 2] = run; cursor[base + 2] = run; run += c2; }
    if (base + 3 < N_NODES) { offsets[base + 3] = run; cursor[base + 3] = run; run += c3; }
}

// ---------------------------------------------------------------------------
// Kernel 5: scatter edges into CSR slots. (col,val) packed as int2 -> one
// 8B store per edge instead of two 4B stores.
// ---------------------------------------------------------------------------
__global__ __launch_bounds__(256) void fill_k(const int* __restrict__ erow,
                                              const int* __restrict__ ecol,
                                              const float* __restrict__ eval,
                                              int* __restrict__ cursor,
                                              int2* __restrict__ csr_cv) {
    int e = blockIdx.x * 256 + threadIdx.x;
    if (e < N_EDGES) {
        int r = erow[e];
        int pos = atomicAdd(&cursor[r], 1);
        csr_cv[pos] = make_int2(ecol[e], __float_as_int(eval[e]));
    }
}

// ---------------------------------------------------------------------------
// Kernel 6: aggregate + ReLU. One wave per node, lane = feature.
// 4-deep ILP unroll: 4 independent (col,val) loads then 4 independent
// support-row gathers in flight -> breaks the per-edge dependent-load chain.
// ---------------------------------------------------------------------------
__global__ __launch_bounds__(256) void agg_k(const int* __restrict__ offsets,
                                             const int2* __restrict__ csr_cv,
                                             const bf16_t* __restrict__ support,
                                             float* __restrict__ out) {
    int node = blockIdx.x * 4 + (threadIdx.x >> 6);
    int lane = threadIdx.x & 63;
    if (node >= N_NODES) return;
    int s = offsets[node];
    int e = offsets[node + 1];
    float acc = 0.f;
    int p = s;
    for (; p + 4 <= e; p += 4) {
        int2 c0 = csr_cv[p + 0];
        int2 c1 = csr_cv[p + 1];
        int2 c2 = csr_cv[p + 2];
        int2 c3 = csr_cv[p + 3];
        float s0 = (float)support[(size_t)c0.x * D_OUT + lane];
        float s1 = (float)support[(size_t)c1.x * D_OUT + lane];
        float s2 = (float)support[(size_t)c2.x * D_OUT + lane];
        float s3 = (float)support[(size_t)c3.x * D_OUT + lane];
        acc = fmaf(__int_as_float(c0.y), s0, acc);
        acc = fmaf(__int_as_float(c1.y), s1, acc);
        acc = fmaf(__int_as_float(c2.y), s2, acc);
        acc = fmaf(__int_as_float(c3.y), s3, acc);
    }
    for (; p < e; ++p) {
        int2 c = csr_cv[p];
        acc = fmaf(__int_as_float(c.y),
                   (float)support[(size_t)c.x * D_OUT + lane], acc);
    }
    out[(size_t)node * D_OUT + lane] = fmaxf(acc, 0.f);
}

extern "C" void kernel_launch(void* const* d_in, const int* in_sizes, int n_in,
                              void* d_out, int out_size, void* d_ws, size_t ws_size,
                              hipStream_t stream) {
    const float* x    = (const float*)d_in[0];
    const int*   erow = (const int*)d_in[1];
    const int*   ecol = (const int*)d_in[2];
    const float* eval = (const float*)d_in[3];
    const float* W    = (const float*)d_in[4];
    float* out = (float*)d_out;

    // ---- workspace layout ----
    char* ws = (char*)d_ws;
    bf16_t* support = (bf16_t*)ws;                                   // 12,800,000 B
    bf16_t* WpackS  = (bf16_t*)(ws + 12800000);                      //     32,768 B
    int*    counts  = (int*)(ws + 12800000 + 32768);                 //    400,000 B
    int*    offsets = counts + N_NODES;                              //    400,004 B
    int*    cursor  = offsets + (N_NODES + 1);                       //    400,000 B
    int2*   csr_cv  = (int2*)(cursor + N_NODES);                     //  9,600,000 B
    int*    bsum    = (int*)(csr_cv + N_EDGES);                      //        392 B
    int*    bpre    = bsum + SCAN_NB;                                //        392 B

    // 1) pack W into bf16 MFMA B-fragments
    pack_w<<<(D_IN * D_OUT + 255) / 256, 256, 0, stream>>>(W, WpackS);

    // 2) support = x @ W (bf16 MFMA)
    gemm_mfma<<<(N_TILES + 3) / 4, 256, 0, stream>>>(x, (const bf16x8*)WpackS, support);

    // 3) CSR build: histogram -> hierarchical scan -> fill
    hipMemsetAsync(counts, 0, (size_t)N_NODES * sizeof(int), stream);
    hist_k<<<(N_EDGES + 255) / 256, 256, 0, stream>>>(erow, counts);
    partial_k<<<SCAN_NB, 256, 0, stream>>>(counts, bsum);
    scan_bsum_k<<<1, 128, 0, stream>>>(bsum, bpre, offsets);
    emit_k<<<SCAN_NB, 256, 0, stream>>>(counts, bpre, offsets, cursor);
    fill_k<<<(N_EDGES + 255) / 256, 256, 0, stream>>>(erow, ecol, eval, cursor,
                                                      csr_cv);

    // 4) aggregate + ReLU (no atomics, writes every output element)
    agg_k<<<(N_NODES + 3) / 4, 256, 0, stream>>>(offsets, csr_cv, support, out);
}

// Round 5
// 202.121 us; speedup vs baseline: 2.7586x; 1.1107x over previous
//
#include <hip/hip_runtime.h>
#include <hip/hip_bf16.h>

#define N_NODES 100000
#define N_EDGES 1200000
#define D_IN 256
#define D_OUT 64
#define N_TILES (N_NODES / 16)                     // 6250 row tiles of 16
#define GEMM_BLOCKS ((N_TILES + 3) / 4)            // 1563
#define EDGE4_BLOCKS ((N_EDGES / 4 + 255) / 256)   // 1172 (4 edges/thread)

#define FILL_PASSES 4
#define PASS_NODES (N_NODES / FILL_PASSES)         // 25000

#define SCAN_BLOCK 1024
#define SCAN_NB ((N_NODES + SCAN_BLOCK - 1) / SCAN_BLOCK) // 98

typedef __bf16 bf16_t;
typedef bf16_t bf16x8 __attribute__((ext_vector_type(8)));
typedef float f32x4 __attribute__((ext_vector_type(4)));

// pack (col, val) into 4B: col<<15 | round(val*32767). val in [0,1).
__device__ __forceinline__ unsigned pack_cv(int col, float val) {
    return ((unsigned)col << 15) | (unsigned)(val * 32767.f + 0.5f);
}

// ---------------------------------------------------------------------------
// Kernel 1: pack W[256][64] (fp32) into MFMA B-fragment order, bf16.
// ---------------------------------------------------------------------------
__global__ __launch_bounds__(256) void pack_w(const float* __restrict__ W,
                                              bf16_t* __restrict__ Wpack) {
    int id = blockIdx.x * 256 + threadIdx.x;
    if (id < D_IN * D_OUT) {
        int i  = id & 7;
        int l  = (id >> 3) & 63;
        int n  = (id >> 9) & 3;
        int kk = id >> 11;
        int k = kk * 32 + (l >> 4) * 8 + i;
        int c = n * 16 + (l & 15);
        Wpack[id] = (bf16_t)W[k * D_OUT + c];
    }
}

// ---------------------------------------------------------------------------
// Kernel 2 (fat): blocks [0, GEMM_BLOCKS) do support = x @ W via MFMA;
// blocks [GEMM_BLOCKS, GEMM_BLOCKS+EDGE4_BLOCKS) do edge histogram + cv pack.
// The two halves are independent; hist/cv latency hides under BW-bound GEMM.
// ---------------------------------------------------------------------------
__global__ __launch_bounds__(256) void gemm_hist_cv(
        const float* __restrict__ x, const bf16x8* __restrict__ Wpack,
        bf16_t* __restrict__ support,
        const int* __restrict__ erow, const int* __restrict__ ecol,
        const float* __restrict__ eval,
        int* __restrict__ counts, unsigned* __restrict__ cv) {
    int bid = blockIdx.x;
    if (bid < GEMM_BLOCKS) {
        int wave = threadIdx.x >> 6;
        int lane = threadIdx.x & 63;
        int tile = bid * 4 + wave;
        if (tile >= N_TILES) return;
        int lrow = lane & 15;
        int g    = lane >> 4;

        const float* __restrict__ xp = x + (size_t)(tile * 16 + lrow) * D_IN + g * 8;

        f32x4 acc0 = {0.f, 0.f, 0.f, 0.f};
        f32x4 acc1 = {0.f, 0.f, 0.f, 0.f};
        f32x4 acc2 = {0.f, 0.f, 0.f, 0.f};
        f32x4 acc3 = {0.f, 0.f, 0.f, 0.f};

#pragma unroll
        for (int kk = 0; kk < 8; ++kk) {
            float4 a0 = *(const float4*)(xp + kk * 32);
            float4 a1 = *(const float4*)(xp + kk * 32 + 4);
            bf16x8 a;
            a[0] = (bf16_t)a0.x; a[1] = (bf16_t)a0.y;
            a[2] = (bf16_t)a0.z; a[3] = (bf16_t)a0.w;
            a[4] = (bf16_t)a1.x; a[5] = (bf16_t)a1.y;
            a[6] = (bf16_t)a1.z; a[7] = (bf16_t)a1.w;

            bf16x8 b0 = Wpack[(kk * 4 + 0) * 64 + lane];
            bf16x8 b1 = Wpack[(kk * 4 + 1) * 64 + lane];
            bf16x8 b2 = Wpack[(kk * 4 + 2) * 64 + lane];
            bf16x8 b3 = Wpack[(kk * 4 + 3) * 64 + lane];

            acc0 = __builtin_amdgcn_mfma_f32_16x16x32_bf16(a, b0, acc0, 0, 0, 0);
            acc1 = __builtin_amdgcn_mfma_f32_16x16x32_bf16(a, b1, acc1, 0, 0, 0);
            acc2 = __builtin_amdgcn_mfma_f32_16x16x32_bf16(a, b2, acc2, 0, 0, 0);
            acc3 = __builtin_amdgcn_mfma_f32_16x16x32_bf16(a, b3, acc3, 0, 0, 0);
        }

        bf16_t* __restrict__ sp = support + (size_t)tile * 16 * D_OUT;
#pragma unroll
        for (int r = 0; r < 4; ++r) {
            int row = g * 4 + r;
            sp[row * D_OUT +  0 + lrow] = (bf16_t)acc0[r];
            sp[row * D_OUT + 16 + lrow] = (bf16_t)acc1[r];
            sp[row * D_OUT + 32 + lrow] = (bf16_t)acc2[r];
            sp[row * D_OUT + 48 + lrow] = (bf16_t)acc3[r];
        }
    } else {
        int t = (bid - GEMM_BLOCKS) * 256 + threadIdx.x;
        int e = t * 4;
        if (e + 3 < N_EDGES) {
            int4   r4 = *(const int4*)(erow + e);
            int4   c4 = *(const int4*)(ecol + e);
            float4 v4 = *(const float4*)(eval + e);
            atomicAdd(&counts[r4.x], 1);
            atomicAdd(&counts[r4.y], 1);
            atomicAdd(&counts[r4.z], 1);
            atomicAdd(&counts[r4.w], 1);
            uint4 o;
            o.x = pack_cv(c4.x, v4.x);
            o.y = pack_cv(c4.y, v4.y);
            o.z = pack_cv(c4.z, v4.z);
            o.w = pack_cv(c4.w, v4.w);
            *(uint4*)(cv + e) = o;
        } else {
            for (int i = 0; i < 4; ++i) {
                if (e + i < N_EDGES) {
                    atomicAdd(&counts[erow[e + i]], 1);
                    cv[e + i] = pack_cv(ecol[e + i], eval[e + i]);
                }
            }
        }
    }
}

// ---------------------------------------------------------------------------
// Kernel 3a: per-block partial sums of counts (1024 counts per block).
// ---------------------------------------------------------------------------
__global__ __launch_bounds__(256) void partial_k(const int* __restrict__ counts,
                                                 int* __restrict__ bsum) {
    int b = blockIdx.x, t = threadIdx.x;
    int base = b * SCAN_BLOCK + t * 4;
    int s = 0;
    if (base + 3 < N_NODES) {
        int4 v = *(const int4*)(counts + base);
        s = v.x + v.y + v.z + v.w;
    } else {
#pragma unroll
        for (int i = 0; i < 4; ++i)
            if (base + i < N_NODES) s += counts[base + i];
    }
#pragma unroll
    for (int off = 32; off > 0; off >>= 1) s += __shfl_down(s, off);
    __shared__ int sh[4];
    if ((t & 63) == 0) sh[t >> 6] = s;
    __syncthreads();
    if (t == 0) bsum[b] = sh[0] + sh[1] + sh[2] + sh[3];
}

// ---------------------------------------------------------------------------
// Kernel 3b: scan the 98 block sums (1 tiny block). Also writes offsets[N].
// ---------------------------------------------------------------------------
__global__ __launch_bounds__(128) void scan_bsum_k(const int* __restrict__ bsum,
                                                   int* __restrict__ bpre,
                                                   int* __restrict__ offsets) {
    __shared__ int sh[128];
    int t = threadIdx.x;
    int v = (t < SCAN_NB) ? bsum[t] : 0;
    sh[t] = v;
    __syncthreads();
    for (int off = 1; off < 128; off <<= 1) {
        int add = (t >= off) ? sh[t - off] : 0;
        __syncthreads();
        sh[t] += add;
        __syncthreads();
    }
    if (t < SCAN_NB) bpre[t] = sh[t] - v;
    if (t == 127) offsets[N_NODES] = sh[127];
}

// ---------------------------------------------------------------------------
// Kernel 3c: block-local scan + global prefix -> offsets, cursor.
// ---------------------------------------------------------------------------
__global__ __launch_bounds__(256) void emit_k(const int* __restrict__ counts,
                                              const int* __restrict__ bpre,
                                              int* __restrict__ offsets,
                                              int* __restrict__ cursor) {
    __shared__ int sh[256];
    int b = blockIdx.x, t = threadIdx.x;
    int base = b * SCAN_BLOCK + t * 4;
    int c0 = 0, c1 = 0, c2 = 0, c3 = 0;
    if (base + 3 < N_NODES) {
        int4 v = *(const int4*)(counts + base);
        c0 = v.x; c1 = v.y; c2 = v.z; c3 = v.w;
    } else {
        if (base + 0 < N_NODES) c0 = counts[base + 0];
        if (base + 1 < N_NODES) c1 = counts[base + 1];
        if (base + 2 < N_NODES) c2 = counts[base + 2];
        if (base + 3 < N_NODES) c3 = counts[base + 3];
    }
    int sum4 = c0 + c1 + c2 + c3;
    sh[t] = sum4;
    __syncthreads();
    for (int off = 1; off < 256; off <<= 1) {
        int add = (t >= off) ? sh[t - off] : 0;
        __syncthreads();
        sh[t] += add;
        __syncthreads();
    }
    int run = bpre[b] + sh[t] - sum4;
    if (base + 0 < N_NODES) { offsets[base + 0] = run; cursor[base + 0] = run; run += c0; }
    if (base + 1 < N_NODES) { offsets[base + 1] = run; cursor[base + 1] = run; run += c1; }
    if (base + 2 < N_NODES) { offsets[base + 2] = run; cursor[base + 2] = run; run += c2; }
    if (base + 3 < N_NODES) { offsets[base + 3] = run; cursor[base + 3] = run; run += c3; }
}

// ---------------------------------------------------------------------------
// Kernel 4: predicated CSR fill, one pass per row range [lo, hi).
// Writes land in a 1.2 MB csr window -> L2-resident, no random DRAM scatter.
// ---------------------------------------------------------------------------
__global__ __launch_bounds__(256) void fill_k(const int* __restrict__ erow,
                                              const unsigned* __restrict__ cv,
                                              int* __restrict__ cursor,
                                              unsigned* __restrict__ csr,
                                              int lo, int hi) {
    int t = blockIdx.x * 256 + threadIdx.x;
    int e = t * 4;
    if (e + 3 < N_EDGES) {
        int4  r4 = *(const int4*)(erow + e);
        uint4 c4 = *(const uint4*)(cv + e);
        if (r4.x >= lo && r4.x < hi) { int p = atomicAdd(&cursor[r4.x], 1); csr[p] = c4.x; }
        if (r4.y >= lo && r4.y < hi) { int p = atomicAdd(&cursor[r4.y], 1); csr[p] = c4.y; }
        if (r4.z >= lo && r4.z < hi) { int p = atomicAdd(&cursor[r4.z], 1); csr[p] = c4.z; }
        if (r4.w >= lo && r4.w < hi) { int p = atomicAdd(&cursor[r4.w], 1); csr[p] = c4.w; }
    } else {
        for (int i = 0; i < 4; ++i) {
            if (e + i < N_EDGES) {
                int r = erow[e + i];
                if (r >= lo && r < hi) {
                    int p = atomicAdd(&cursor[r], 1);
                    csr[p] = cv[e + i];
                }
            }
        }
    }
}

// ---------------------------------------------------------------------------
// Kernel 5: aggregate + ReLU. One wave per node, lane = feature.
// 8-deep ILP: 8 independent csr loads then 8 independent support gathers.
// ---------------------------------------------------------------------------
__global__ __launch_bounds__(256) void agg_k(const int* __restrict__ offsets,
                                             const unsigned* __restrict__ csr,
                                             const bf16_t* __restrict__ support,
                                             float* __restrict__ out) {
    int node = blockIdx.x * 4 + (threadIdx.x >> 6);
    int lane = threadIdx.x & 63;
    if (node >= N_NODES) return;
    int s = offsets[node];
    int e = offsets[node + 1];
    const float inv = 1.f / 32767.f;
    float acc = 0.f;
    int p = s;
    for (; p + 8 <= e; p += 8) {
        unsigned w0 = csr[p + 0], w1 = csr[p + 1], w2 = csr[p + 2], w3 = csr[p + 3];
        unsigned w4 = csr[p + 4], w5 = csr[p + 5], w6 = csr[p + 6], w7 = csr[p + 7];
        float s0 = (float)support[(size_t)(w0 >> 15) * D_OUT + lane];
        float s1 = (float)support[(size_t)(w1 >> 15) * D_OUT + lane];
        float s2 = (float)support[(size_t)(w2 >> 15) * D_OUT + lane];
        float s3 = (float)support[(size_t)(w3 >> 15) * D_OUT + lane];
        float s4 = (float)support[(size_t)(w4 >> 15) * D_OUT + lane];
        float s5 = (float)support[(size_t)(w5 >> 15) * D_OUT + lane];
        float s6 = (float)support[(size_t)(w6 >> 15) * D_OUT + lane];
        float s7 = (float)support[(size_t)(w7 >> 15) * D_OUT + lane];
        acc = fmaf((float)(w0 & 0x7fffu) * inv, s0, acc);
        acc = fmaf((float)(w1 & 0x7fffu) * inv, s1, acc);
        acc = fmaf((float)(w2 & 0x7fffu) * inv, s2, acc);
        acc = fmaf((float)(w3 & 0x7fffu) * inv, s3, acc);
        acc = fmaf((float)(w4 & 0x7fffu) * inv, s4, acc);
        acc = fmaf((float)(w5 & 0x7fffu) * inv, s5, acc);
        acc = fmaf((float)(w6 & 0x7fffu) * inv, s6, acc);
        acc = fmaf((float)(w7 & 0x7fffu) * inv, s7, acc);
    }
    for (; p + 4 <= e; p += 4) {
        unsigned w0 = csr[p + 0], w1 = csr[p + 1], w2 = csr[p + 2], w3 = csr[p + 3];
        float s0 = (float)support[(size_t)(w0 >> 15) * D_OUT + lane];
        float s1 = (float)support[(size_t)(w1 >> 15) * D_OUT + lane];
        float s2 = (float)support[(size_t)(w2 >> 15) * D_OUT + lane];
        float s3 = (float)support[(size_t)(w3 >> 15) * D_OUT + lane];
        acc = fmaf((float)(w0 & 0x7fffu) * inv, s0, acc);
        acc = fmaf((float)(w1 & 0x7fffu) * inv, s1, acc);
        acc = fmaf((float)(w2 & 0x7fffu) * inv, s2, acc);
        acc = fmaf((float)(w3 & 0x7fffu) * inv, s3, acc);
    }
    for (; p < e; ++p) {
        unsigned w = csr[p];
        acc = fmaf((float)(w & 0x7fffu) * inv,
                   (float)support[(size_t)(w >> 15) * D_OUT + lane], acc);
    }
    out[(size_t)node * D_OUT + lane] = fmaxf(acc, 0.f);
}

extern "C" void kernel_launch(void* const* d_in, const int* in_sizes, int n_in,
                              void* d_out, int out_size, void* d_ws, size_t ws_size,
                              hipStream_t stream) {
    const float* x    = (const float*)d_in[0];
    const int*   erow = (const int*)d_in[1];
    const int*   ecol = (const int*)d_in[2];
    const float* eval = (const float*)d_in[3];
    const float* W    = (const float*)d_in[4];
    float* out = (float*)d_out;

    // ---- workspace layout (16B-aligned segments, ~23.6 MB) ----
    char* ws = (char*)d_ws;
    bf16_t*   support = (bf16_t*)ws;                         // 12,800,000
    bf16_t*   WpackS  = (bf16_t*)(ws + 12800000);            //     32,768
    int*      counts  = (int*)(ws + 12832768);               //    400,000
    int*      offsets = (int*)(ws + 13232768);               //    400,004
    int*      cursor  = (int*)(ws + 13632896);               //    400,000
    unsigned* cv      = (unsigned*)(ws + 14032896);          //  4,800,000
    unsigned* csr     = (unsigned*)(ws + 18832896);          //  4,800,000
    int*      bsum    = (int*)(ws + 23632896);               //        392
    int*      bpre    = (int*)(ws + 23633288);               //        392

    // 1) pack W into bf16 MFMA B-fragments
    pack_w<<<(D_IN * D_OUT + 255) / 256, 256, 0, stream>>>(W, WpackS);

    // 2) zero counts, then fused GEMM + histogram + cv pack
    hipMemsetAsync(counts, 0, (size_t)N_NODES * sizeof(int), stream);
    gemm_hist_cv<<<GEMM_BLOCKS + EDGE4_BLOCKS, 256, 0, stream>>>(
        x, (const bf16x8*)WpackS, support, erow, ecol, eval, counts, cv);

    // 3) hierarchical scan -> offsets, cursor
    partial_k<<<SCAN_NB, 256, 0, stream>>>(counts, bsum);
    scan_bsum_k<<<1, 128, 0, stream>>>(bsum, bpre, offsets);
    emit_k<<<SCAN_NB, 256, 0, stream>>>(counts, bpre, offsets, cursor);

    // 4) predicated CSR fill, 4 L2-localized passes
    for (int p = 0; p < FILL_PASSES; ++p) {
        fill_k<<<EDGE4_BLOCKS, 256, 0, stream>>>(erow, cv, cursor, csr,
                                                 p * PASS_NODES, (p + 1) * PASS_NODES);
    }

    // 5) aggregate + ReLU (no atomics, writes every output element)
    agg_k<<<(N_NODES + 3) / 4, 256, 0, stream>>>(offsets, csr, support, out);
}

// Round 6
// 186.319 us; speedup vs baseline: 2.9925x; 1.0848x over previous
//
#include <hip/hip_runtime.h>
#include <hip/hip_bf16.h>

#define N_NODES 100000
#define N_EDGES 1200000
#define D_IN 256
#define D_OUT 64
#define N_TILES (N_NODES / 16)                     // 6250 row tiles of 16

// fused kernel striping: period 5 = 2 GEMM blocks + 3 edge blocks
#define TILES_PER_BLOCK 8                          // 4 waves x 2 tiles
#define GEMM_NB ((N_TILES + TILES_PER_BLOCK - 1) / TILES_PER_BLOCK) // 782
#define EDGE4_NB ((N_EDGES / 4 + 255) / 256)       // 1172 (4 edges/thread)
#define STRIPE_P ((GEMM_NB + 1) / 2)               // 391 periods
#define FUSED_NB (STRIPE_P * 5)                    // 1955

#define FILL_PASSES 2
#define PASS_NODES (N_NODES / FILL_PASSES)         // 50000
#define FILL_NB EDGE4_NB

#define SCAN_BLOCK 1024
#define SCAN_NB ((N_NODES + SCAN_BLOCK - 1) / SCAN_BLOCK) // 98

typedef __bf16 bf16_t;
typedef bf16_t bf16x8 __attribute__((ext_vector_type(8)));
typedef float f32x4 __attribute__((ext_vector_type(4)));

// pack (col, val) into 4B: col<<15 | round(val*32767). val in [0,1).
__device__ __forceinline__ unsigned pack_cv(int col, float val) {
    return ((unsigned)col << 15) | (unsigned)(val * 32767.f + 0.5f);
}

// ---------------------------------------------------------------------------
// Kernel 1: pack W[256][64] (fp32) into MFMA B-fragment order, bf16.
// ---------------------------------------------------------------------------
__global__ __launch_bounds__(256) void pack_w(const float* __restrict__ W,
                                              bf16_t* __restrict__ Wpack) {
    int id = blockIdx.x * 256 + threadIdx.x;
    if (id < D_IN * D_OUT) {
        int i  = id & 7;
        int l  = (id >> 3) & 63;
        int n  = (id >> 9) & 3;
        int kk = id >> 11;
        int k = kk * 32 + (l >> 4) * 8 + i;
        int c = n * 16 + (l & 15);
        Wpack[id] = (bf16_t)W[k * D_OUT + c];
    }
}

// ---------------------------------------------------------------------------
// Kernel 2 (fused, striped): period-5 block roles -> 2 GEMM : 3 edge.
// GEMM: Wpack staged to LDS (ds_read b-frags, short chain); 2 tiles/wave
// (doubled independent x-loads). Edge: histogram + cv pack, co-resident
// with GEMM so its atomics hide under GEMM's memory latency.
// ---------------------------------------------------------------------------
__global__ __launch_bounds__(256, 4) void gemm_hist_cv(
        const float* __restrict__ x, const bf16x8* __restrict__ Wpack,
        bf16_t* __restrict__ support,
        const int* __restrict__ erow, const int* __restrict__ ecol,
        const float* __restrict__ eval,
        int* __restrict__ counts, unsigned* __restrict__ cv) {
    __shared__ bf16x8 Wlds[2048];                  // 32 KB
    int p = blockIdx.x / 5;
    int r = blockIdx.x % 5;
    if (r < 2) {
        // ---------------- GEMM role ----------------
        int gb = p * 2 + r;                        // 0..781
        // stage Wpack -> LDS (all 256 threads; uniform branch, barrier legal)
        {
            int t = threadIdx.x;
#pragma unroll
            for (int i = 0; i < 8; ++i)
                Wlds[t + i * 256] = Wpack[t + i * 256];
        }
        __syncthreads();

        int wave = threadIdx.x >> 6;
        int lane = threadIdx.x & 63;
        int lrow = lane & 15;
        int g    = lane >> 4;
        int tileA = gb * TILES_PER_BLOCK + wave * 2;
        int tileB = tileA + 1;
        bool vA = (tileA < N_TILES);
        bool vB = (tileB < N_TILES);
        int tA = vA ? tileA : 0;
        int tB = vB ? tileB : 0;

        const float* __restrict__ xpA = x + (size_t)(tA * 16 + lrow) * D_IN + g * 8;
        const float* __restrict__ xpB = x + (size_t)(tB * 16 + lrow) * D_IN + g * 8;

        f32x4 a0 = {0.f,0.f,0.f,0.f}, a1 = a0, a2 = a0, a3 = a0;
        f32x4 b0 = a0, b1 = a0, b2 = a0, b3 = a0;

#pragma unroll
        for (int kk = 0; kk < 8; ++kk) {
            float4 xA0 = *(const float4*)(xpA + kk * 32);
            float4 xA1 = *(const float4*)(xpA + kk * 32 + 4);
            float4 xB0 = *(const float4*)(xpB + kk * 32);
            float4 xB1 = *(const float4*)(xpB + kk * 32 + 4);
            bf16x8 aA, aB;
            aA[0] = (bf16_t)xA0.x; aA[1] = (bf16_t)xA0.y;
            aA[2] = (bf16_t)xA0.z; aA[3] = (bf16_t)xA0.w;
            aA[4] = (bf16_t)xA1.x; aA[5] = (bf16_t)xA1.y;
            aA[6] = (bf16_t)xA1.z; aA[7] = (bf16_t)xA1.w;
            aB[0] = (bf16_t)xB0.x; aB[1] = (bf16_t)xB0.y;
            aB[2] = (bf16_t)xB0.z; aB[3] = (bf16_t)xB0.w;
            aB[4] = (bf16_t)xB1.x; aB[5] = (bf16_t)xB1.y;
            aB[6] = (bf16_t)xB1.z; aB[7] = (bf16_t)xB1.w;

            bf16x8 w0 = Wlds[(kk * 4 + 0) * 64 + lane];
            bf16x8 w1 = Wlds[(kk * 4 + 1) * 64 + lane];
            bf16x8 w2 = Wlds[(kk * 4 + 2) * 64 + lane];
            bf16x8 w3 = Wlds[(kk * 4 + 3) * 64 + lane];

            a0 = __builtin_amdgcn_mfma_f32_16x16x32_bf16(aA, w0, a0, 0, 0, 0);
            a1 = __builtin_amdgcn_mfma_f32_16x16x32_bf16(aA, w1, a1, 0, 0, 0);
            a2 = __builtin_amdgcn_mfma_f32_16x16x32_bf16(aA, w2, a2, 0, 0, 0);
            a3 = __builtin_amdgcn_mfma_f32_16x16x32_bf16(aA, w3, a3, 0, 0, 0);
            b0 = __builtin_amdgcn_mfma_f32_16x16x32_bf16(aB, w0, b0, 0, 0, 0);
            b1 = __builtin_amdgcn_mfma_f32_16x16x32_bf16(aB, w1, b1, 0, 0, 0);
            b2 = __builtin_amdgcn_mfma_f32_16x16x32_bf16(aB, w2, b2, 0, 0, 0);
            b3 = __builtin_amdgcn_mfma_f32_16x16x32_bf16(aB, w3, b3, 0, 0, 0);
        }

        if (vA) {
            bf16_t* __restrict__ sp = support + (size_t)tA * 16 * D_OUT;
#pragma unroll
            for (int q = 0; q < 4; ++q) {
                int row = g * 4 + q;
                sp[row * D_OUT +  0 + lrow] = (bf16_t)a0[q];
                sp[row * D_OUT + 16 + lrow] = (bf16_t)a1[q];
                sp[row * D_OUT + 32 + lrow] = (bf16_t)a2[q];
                sp[row * D_OUT + 48 + lrow] = (bf16_t)a3[q];
            }
        }
        if (vB) {
            bf16_t* __restrict__ sp = support + (size_t)tB * 16 * D_OUT;
#pragma unroll
            for (int q = 0; q < 4; ++q) {
                int row = g * 4 + q;
                sp[row * D_OUT +  0 + lrow] = (bf16_t)b0[q];
                sp[row * D_OUT + 16 + lrow] = (bf16_t)b1[q];
                sp[row * D_OUT + 32 + lrow] = (bf16_t)b2[q];
                sp[row * D_OUT + 48 + lrow] = (bf16_t)b3[q];
            }
        }
    } else {
        // ---------------- edge role: histogram + cv pack ----------------
        int eb = p * 3 + (r - 2);                  // 0..1171
        if (eb >= EDGE4_NB) return;
        int e = (eb * 256 + threadIdx.x) * 4;
        if (e + 3 < N_EDGES) {
            int4   r4 = *(const int4*)(erow + e);
            int4   c4 = *(const int4*)(ecol + e);
            float4 v4 = *(const float4*)(eval + e);
            atomicAdd(&counts[r4.x], 1);
            atomicAdd(&counts[r4.y], 1);
            atomicAdd(&counts[r4.z], 1);
            atomicAdd(&counts[r4.w], 1);
            uint4 o;
            o.x = pack_cv(c4.x, v4.x);
            o.y = pack_cv(c4.y, v4.y);
            o.z = pack_cv(c4.z, v4.z);
            o.w = pack_cv(c4.w, v4.w);
            *(uint4*)(cv + e) = o;
        } else {
            for (int i = 0; i < 4; ++i) {
                if (e + i < N_EDGES) {
                    atomicAdd(&counts[erow[e + i]], 1);
                    cv[e + i] = pack_cv(ecol[e + i], eval[e + i]);
                }
            }
        }
    }
}

// ---------------------------------------------------------------------------
// Kernel 3a: per-block partial sums of counts (1024 counts per block).
// ---------------------------------------------------------------------------
__global__ __launch_bounds__(256) void partial_k(const int* __restrict__ counts,
                                                 int* __restrict__ bsum) {
    int b = blockIdx.x, t = threadIdx.x;
    int base = b * SCAN_BLOCK + t * 4;
    int s = 0;
    if (base + 3 < N_NODES) {
        int4 v = *(const int4*)(counts + base);
        s = v.x + v.y + v.z + v.w;
    } else {
#pragma unroll
        for (int i = 0; i < 4; ++i)
            if (base + i < N_NODES) s += counts[base + i];
    }
#pragma unroll
    for (int off = 32; off > 0; off >>= 1) s += __shfl_down(s, off);
    __shared__ int sh[4];
    if ((t & 63) == 0) sh[t >> 6] = s;
    __syncthreads();
    if (t == 0) bsum[b] = sh[0] + sh[1] + sh[2] + sh[3];
}

// ---------------------------------------------------------------------------
// Kernel 3b: scan the 98 block sums (1 tiny block). Also writes offsets[N].
// ---------------------------------------------------------------------------
__global__ __launch_bounds__(128) void scan_bsum_k(const int* __restrict__ bsum,
                                                   int* __restrict__ bpre,
                                                   int* __restrict__ offsets) {
    __shared__ int sh[128];
    int t = threadIdx.x;
    int v = (t < SCAN_NB) ? bsum[t] : 0;
    sh[t] = v;
    __syncthreads();
    for (int off = 1; off < 128; off <<= 1) {
        int add = (t >= off) ? sh[t - off] : 0;
        __syncthreads();
        sh[t] += add;
        __syncthreads();
    }
    if (t < SCAN_NB) bpre[t] = sh[t] - v;
    if (t == 127) offsets[N_NODES] = sh[127];
}

// ---------------------------------------------------------------------------
// Kernel 3c: block-local scan + global prefix -> offsets, cursor.
// ---------------------------------------------------------------------------
__global__ __launch_bounds__(256) void emit_k(const int* __restrict__ counts,
                                              const int* __restrict__ bpre,
                                              int* __restrict__ offsets,
                                              int* __restrict__ cursor) {
    __shared__ int sh[256];
    int b = blockIdx.x, t = threadIdx.x;
    int base = b * SCAN_BLOCK + t * 4;
    int c0 = 0, c1 = 0, c2 = 0, c3 = 0;
    if (base + 3 < N_NODES) {
        int4 v = *(const int4*)(counts + base);
        c0 = v.x; c1 = v.y; c2 = v.z; c3 = v.w;
    } else {
        if (base + 0 < N_NODES) c0 = counts[base + 0];
        if (base + 1 < N_NODES) c1 = counts[base + 1];
        if (base + 2 < N_NODES) c2 = counts[base + 2];
        if (base + 3 < N_NODES) c3 = counts[base + 3];
    }
    int sum4 = c0 + c1 + c2 + c3;
    sh[t] = sum4;
    __syncthreads();
    for (int off = 1; off < 256; off <<= 1) {
        int add = (t >= off) ? sh[t - off] : 0;
        __syncthreads();
        sh[t] += add;
        __syncthreads();
    }
    int run = bpre[b] + sh[t] - sum4;
    if (base + 0 < N_NODES) { offsets[base + 0] = run; cursor[base + 0] = run; run += c0; }
    if (base + 1 < N_NODES) { offsets[base + 1] = run; cursor[base + 1] = run; run += c1; }
    if (base + 2 < N_NODES) { offsets[base + 2] = run; cursor[base + 2] = run; run += c2; }
    if (base + 3 < N_NODES) { offsets[base + 3] = run; cursor[base + 3] = run; run += c3; }
}

// ---------------------------------------------------------------------------
// Kernel 4: predicated CSR fill, one pass per row range [lo, hi).
// Writes land in a 2.4 MB csr window -> per-XCD-L2-resident.
// ---------------------------------------------------------------------------
__global__ __launch_bounds__(256) void fill_k(const int* __restrict__ erow,
                                              const unsigned* __restrict__ cv,
                                              int* __restrict__ cursor,
                                              unsigned* __restrict__ csr,
                                              int lo, int hi) {
    int t = blockIdx.x * 256 + threadIdx.x;
    int e = t * 4;
    if (e + 3 < N_EDGES) {
        int4  r4 = *(const int4*)(erow + e);
        uint4 c4 = *(const uint4*)(cv + e);
        if (r4.x >= lo && r4.x < hi) { int q = atomicAdd(&cursor[r4.x], 1); csr[q] = c4.x; }
        if (r4.y >= lo && r4.y < hi) { int q = atomicAdd(&cursor[r4.y], 1); csr[q] = c4.y; }
        if (r4.z >= lo && r4.z < hi) { int q = atomicAdd(&cursor[r4.z], 1); csr[q] = c4.z; }
        if (r4.w >= lo && r4.w < hi) { int q = atomicAdd(&cursor[r4.w], 1); csr[q] = c4.w; }
    } else {
        for (int i = 0; i < 4; ++i) {
            if (e + i < N_EDGES) {
                int r = erow[e + i];
                if (r >= lo && r < hi) {
                    int q = atomicAdd(&cursor[r], 1);
                    csr[q] = cv[e + i];
                }
            }
        }
    }
}

// ---------------------------------------------------------------------------
// Kernel 5: aggregate + ReLU. One wave per node, lane = feature.
// 8-deep ILP: 8 independent csr loads then 8 independent support gathers.
// ---------------------------------------------------------------------------
__global__ __launch_bounds__(256) void agg_k(const int* __restrict__ offsets,
                                             const unsigned* __restrict__ csr,
                                             const bf16_t* __restrict__ support,
                                             float* __restrict__ out) {
    int node = blockIdx.x * 4 + (threadIdx.x >> 6);
    int lane = threadIdx.x & 63;
    if (node >= N_NODES) return;
    int s = offsets[node];
    int e = offsets[node + 1];
    const float inv = 1.f / 32767.f;
    float acc = 0.f;
    int p = s;
    for (; p + 8 <= e; p += 8) {
        unsigned w0 = csr[p + 0], w1 = csr[p + 1], w2 = csr[p + 2], w3 = csr[p + 3];
        unsigned w4 = csr[p + 4], w5 = csr[p + 5], w6 = csr[p + 6], w7 = csr[p + 7];
        float s0 = (float)support[(size_t)(w0 >> 15) * D_OUT + lane];
        float s1 = (float)support[(size_t)(w1 >> 15) * D_OUT + lane];
        float s2 = (float)support[(size_t)(w2 >> 15) * D_OUT + lane];
        float s3 = (float)support[(size_t)(w3 >> 15) * D_OUT + lane];
        float s4 = (float)support[(size_t)(w4 >> 15) * D_OUT + lane];
        float s5 = (float)support[(size_t)(w5 >> 15) * D_OUT + lane];
        float s6 = (float)support[(size_t)(w6 >> 15) * D_OUT + lane];
        float s7 = (float)support[(size_t)(w7 >> 15) * D_OUT + lane];
        acc = fmaf((float)(w0 & 0x7fffu) * inv, s0, acc);
        acc = fmaf((float)(w1 & 0x7fffu) * inv, s1, acc);
        acc = fmaf((float)(w2 & 0x7fffu) * inv, s2, acc);
        acc = fmaf((float)(w3 & 0x7fffu) * inv, s3, acc);
        acc = fmaf((float)(w4 & 0x7fffu) * inv, s4, acc);
        acc = fmaf((float)(w5 & 0x7fffu) * inv, s5, acc);
        acc = fmaf((float)(w6 & 0x7fffu) * inv, s6, acc);
        acc = fmaf((float)(w7 & 0x7fffu) * inv, s7, acc);
    }
    for (; p + 4 <= e; p += 4) {
        unsigned w0 = csr[p + 0], w1 = csr[p + 1], w2 = csr[p + 2], w3 = csr[p + 3];
        float s0 = (float)support[(size_t)(w0 >> 15) * D_OUT + lane];
        float s1 = (float)support[(size_t)(w1 >> 15) * D_OUT + lane];
        float s2 = (float)support[(size_t)(w2 >> 15) * D_OUT + lane];
        float s3 = (float)support[(size_t)(w3 >> 15) * D_OUT + lane];
        acc = fmaf((float)(w0 & 0x7fffu) * inv, s0, acc);
        acc = fmaf((float)(w1 & 0x7fffu) * inv, s1, acc);
        acc = fmaf((float)(w2 & 0x7fffu) * inv, s2, acc);
        acc = fmaf((float)(w3 & 0x7fffu) * inv, s3, acc);
    }
    for (; p < e; ++p) {
        unsigned w = csr[p];
        acc = fmaf((float)(w & 0x7fffu) * inv,
                   (float)support[(size_t)(w >> 15) * D_OUT + lane], acc);
    }
    out[(size_t)node * D_OUT + lane] = fmaxf(acc, 0.f);
}

extern "C" void kernel_launch(void* const* d_in, const int* in_sizes, int n_in,
                              void* d_out, int out_size, void* d_ws, size_t ws_size,
                              hipStream_t stream) {
    const float* x    = (const float*)d_in[0];
    const int*   erow = (const int*)d_in[1];
    const int*   ecol = (const int*)d_in[2];
    const float* eval = (const float*)d_in[3];
    const float* W    = (const float*)d_in[4];
    float* out = (float*)d_out;

    // ---- workspace layout (16B-aligned segments, ~23.6 MB) ----
    char* ws = (char*)d_ws;
    bf16_t*   support = (bf16_t*)ws;                         // 12,800,000
    bf16_t*   WpackS  = (bf16_t*)(ws + 12800000);            //     32,768
    int*      counts  = (int*)(ws + 12832768);               //    400,000
    int*      offsets = (int*)(ws + 13232768);               //    400,004
    int*      cursor  = (int*)(ws + 13632896);               //    400,000
    unsigned* cv      = (unsigned*)(ws + 14032896);          //  4,800,000
    unsigned* csr     = (unsigned*)(ws + 18832896);          //  4,800,000
    int*      bsum    = (int*)(ws + 23632896);               //        392
    int*      bpre    = (int*)(ws + 23633288);               //        392

    // 1) pack W into bf16 MFMA B-fragments
    pack_w<<<(D_IN * D_OUT + 255) / 256, 256, 0, stream>>>(W, WpackS);

    // 2) zero counts, then fused (striped) GEMM + histogram + cv pack
    hipMemsetAsync(counts, 0, (size_t)N_NODES * sizeof(int), stream);
    gemm_hist_cv<<<FUSED_NB, 256, 0, stream>>>(
        x, (const bf16x8*)WpackS, support, erow, ecol, eval, counts, cv);

    // 3) hierarchical scan -> offsets, cursor
    partial_k<<<SCAN_NB, 256, 0, stream>>>(counts, bsum);
    scan_bsum_k<<<1, 128, 0, stream>>>(bsum, bpre, offsets);
    emit_k<<<SCAN_NB, 256, 0, stream>>>(counts, bpre, offsets, cursor);

    // 4) predicated CSR fill, 2 L2-localized passes
    for (int p = 0; p < FILL_PASSES; ++p) {
        fill_k<<<FILL_NB, 256, 0, stream>>>(erow, cv, cursor, csr,
                                            p * PASS_NODES, (p + 1) * PASS_NODES);
    }

    // 5) aggregate + ReLU (no atomics, writes every output element)
    agg_k<<<(N_NODES + 3) / 4, 256, 0, stream>>>(offsets, csr, support, out);
}